// Round 5
// baseline (594.825 us; speedup 1.0000x reference)
//
#include <hip/hip_runtime.h>

// Batched Hungarian matcher — exact LSA, scipy-TRAJECTORY-exact.
//
// R10: R9 (517us, passed, absmax 0) + relax-loop thinning. The relax body
// runs 64 wave-k-units over 4 SIMDs every pop: each instruction removed
// from it saves 16cy/pop. Two exactness-preserving cuts:
//   - NaN-poison for scanned columns: when column bj pops, its owner lane
//     sets shr[k]=NaN (bj = tid + k*512 has a unique (lane,k) solution, so
//     an unconditional per-k cmp_eq+cndmask does it). IEEE ordered-< then
//     makes NaN fail BOTH the update test (r < NaN == false => no
//     shr/path update, == scipy's ~SC mask) and the selection test
//     (NaN < bv == false => never re-popped). Eliminates the per-k scmask
//     bit-test AND the sj=scb?INF:shr cndmask pair.
//   - path in registers: pathv[k] = upd ? i : pathv[k] (1 cndmask)
//     replaces the per-k exec-masked ds_write_b16. A column's path is
//     final at its pop and only read (augment walk) after it popped, so
//     publishing all 8 pathv to path_lds ONCE at search end (before the
//     existing barrier) is sufficient; never-popped columns' stale values
//     are never read.
// Kept from R9: meta=(j<<8)|(r4+1) carried in the reduce (lowest-j
// tie-break preserved by integer order), wave-distributed row-data cache
// with shfl fetch, lane&7 cross-wave mini-reduce, uniform-ich hoist.
// Evaluation order ((minv + cf) - u) - v, strictly-better updates, pop
// sequence and tie-breaks bit-identical to scipy's _lsa.

#define Bb 32
#define Nn 4096
#define Mm 128
#define Tt 512
#define Kk (Nn / Tt)   // 8 columns per thread
#define TSH 9          // log2(Tt)
#define NW (Tt / 64)   // 8 waves
#define RECMAX 160

__global__ __launch_bounds__(Tt, 1)
void hungarian_kernel(const float* __restrict__ predict_scores,
                      const float* __restrict__ predict_points,
                      const int*   __restrict__ scores,
                      const float* __restrict__ points,
                      int* __restrict__ out)
{
    __shared__ double vvl[Nn];           // column duals v (exact f64)
    __shared__ short  path_lds[Nn];      // predecessor row per column
    __shared__ short  row4col[Nn];       // matched row per column (-1 free)
    __shared__ double uu[Mm];            // row duals u
    __shared__ short  col4row[Mm];       // matched column per row (-1 free)
    __shared__ double srow_val[Mm];      // shortest[col4row[i]] at scan time
    __shared__ unsigned char SRr[Mm];    // scanned-row flags
    __shared__ float  tx0[Mm], tx1[Mm];
    __shared__ int    tch[Mm];
    __shared__ short  scol[RECMAX];      // popped (SC) columns this search
    __shared__ double sval[RECMAX];      // their pop values
    __shared__ int    nsc_lds;
    __shared__ double wv_[2][NW];        // per-wave candidate: value
    __shared__ int    wm_[2][NW];        //   meta (j<<8 | (r4+1))

    const int b    = blockIdx.x;
    const int tid  = threadIdx.x;
    const int lane = tid & 63;
    const int wid  = tid >> 6;
    const double INFD = __builtin_inf();
    const double NAND = __builtin_nan("");

    // ---- per-column data -> registers ----
    float negp0[Kk], negp1[Kk], qx0[Kk], qx1[Kk];
    const float* ps = predict_scores + (size_t)b * Nn * 2;
    const float* pp = predict_points + (size_t)b * Nn * 2;
    #pragma unroll
    for (int k = 0; k < Kk; ++k) {
        int j = tid + (k << TSH);
        float2 sc = ((const float2*)ps)[j];
        float mx = fmaxf(sc.x, sc.y);
        float e0 = expf(sc.x - mx), e1 = expf(sc.y - mx);
        float sm = e0 + e1;
        float n0 = -(e0 / sm), n1 = -(e1 / sm);
        float2 qp = ((const float2*)pp)[j];
        negp0[k] = n0; negp1[k] = n1;
        qx0[k] = qp.x; qx1[k] = qp.y;
        vvl[j] = 0.0;
        row4col[j] = -1;
    }
    if (tid < Mm) {
        col4row[tid] = -1;
        SRr[tid] = 0;
        uu[tid] = 0.0;                    // scipy: duals start at zero
        tx0[tid] = points[(size_t)b * Mm * 2 + 2 * tid];
        tx1[tid] = points[(size_t)b * Mm * 2 + 2 * tid + 1];
        tch[tid] = scores[(size_t)b * Mm + tid];
    }
    __syncthreads();

    // ---- wave-distributed row-data cache: lane l holds rows l, l+64 ----
    const float t0_c0 = tx0[lane], t0_c1 = tx0[lane + 64];
    const float t1_c0 = tx1[lane], t1_c1 = tx1[lane + 64];
    const int   ch_c0 = tch[lane], ch_c1 = tch[lane + 64];

    int pathv[Kk];                        // register path (published per search)
    #pragma unroll
    for (int k = 0; k < Kk; ++k) pathv[k] = 0;

    // relax body: PRES = per-class presence array (uniform per pop).
    // NaN-poisoned shr[k] (scanned cols): r < NaN and NaN < bv both false.
    #define RELAX(PRES)                                                        \
        _Pragma("unroll")                                                      \
        for (int k = 0; k < Kk; ++k) {                                         \
            float cf = PRES[k] + (fabsf(qx0[k] - it0) + fabsf(qx1[k] - it1));  \
            double r = ((minv + (double)cf) - ui) - vreg[k];                   \
            bool upd = r < shr[k];                                             \
            shr[k] = upd ? r : shr[k];                                         \
            pathv[k] = upd ? i : pathv[k];                                     \
            double sj = shr[k];                                                \
            if (sj < bv) { bv = sj; bm = premeta[k]; }                         \
        }

    // ---- JV: one shortest-augmenting-path search per row, scipy order ----
    for (int cur_row = 0; cur_row < Mm; ++cur_row) {
        // per-search register preload (constant within the search)
        double shr[Kk], vreg[Kk];
        int    premeta[Kk];
        double u_c0 = uu[lane], u_c1 = uu[lane + 64];   // u changes between searches
        #pragma unroll
        for (int k = 0; k < Kk; ++k) {
            int j = tid + (k << TSH);
            shr[k]  = INFD;
            vreg[k] = vvl[j];
            premeta[k] = (j << 8) | ((int)row4col[j] + 1);  // linear, conflict-free
        }
        int    i = cur_row;
        double minv = 0.0;
        int    sink = -1, par = 0, nsc = 0;
        double ui  = uu[cur_row];
        float  it0 = tx0[cur_row], it1 = tx1[cur_row];
        int    ich = __builtin_amdgcn_readfirstlane((tch[cur_row] == 1) ? 1 : 0);

        for (;;) {
            // ---- relax row i over all 4096 columns (exact f64, scipy order) ----
            double bv = INFD; int bm = 0x7FFFFFFF;
            if (ich) { RELAX(negp1) } else { RELAX(negp0) }

            // ---- wave butterfly: all lanes get wave-min (bv, bm) ----
            #pragma unroll
            for (int off = 32; off > 0; off >>= 1) {
                double ov = __shfl_xor(bv, off);
                int    om = __shfl_xor(bm, off);
                if (ov < bv || (ov == bv && om < bm)) { bv = ov; bm = om; }
            }
            if (lane == 0) { wv_[par][wid] = bv; wm_[par][wid] = bm; }
            __syncthreads();

            // ---- cross-wave: lane&7 reads ONE candidate, 3-step mini-reduce
            //      -> all 64 lanes hold the global (mv, mm) ----
            int l8 = lane & 7;
            double mv = wv_[par][l8];
            int    mm = wm_[par][l8];
            #pragma unroll
            for (int off = 1; off < 8; off <<= 1) {
                double ov = __shfl_xor(mv, off);
                int    om = __shfl_xor(mm, off);
                if (ov < mv || (ov == mv && om < mm)) { mv = ov; mm = om; }
            }
            par ^= 1;
            minv = mv;
            int bj = __builtin_amdgcn_readfirstlane(mm >> 8);
            int r4 = __builtin_amdgcn_readfirstlane((mm & 0xFF) - 1);
            if (r4 < 0) {
                if (tid == 0) nsc_lds = nsc;
                sink = bj;
                break;                             // uniform exit
            }
            // NaN-poison the popped column (scipy: SC[bj]=True). Exactly one
            // (lane,k) satisfies bj == tid + (k<<TSH).
            {
                int s2 = bj - tid;
                #pragma unroll
                for (int k = 0; k < Kk; ++k)
                    if (s2 == (k << TSH)) shr[k] = NAND;
            }
            if (tid == 0) {
                SRr[r4] = 1; srow_val[r4] = mv;
                scol[nsc] = (short)bj; sval[nsc] = mv; ++nsc;
            }
            // ---- next scan row's data via wave-distributed shfl (no LDS) ----
            i = r4;
            {
                int hi = r4 >> 6, lx = r4 & 63;
                double us = hi ? u_c1 : u_c0;
                float  f0 = hi ? t0_c1 : t0_c0;
                float  f1 = hi ? t1_c1 : t1_c0;
                int    cs = hi ? ch_c1 : ch_c0;
                ui  = __shfl(us, lx);
                it0 = __shfl(f0, lx);
                it1 = __shfl(f1, lx);
                ich = __builtin_amdgcn_readfirstlane(__shfl(cs, lx) == 1 ? 1 : 0);
            }
        }

        // ---- publish register paths (popped columns' values are final;
        //      never-popped columns' entries are never read) ----
        #pragma unroll
        for (int k = 0; k < Kk; ++k)
            path_lds[tid + (k << TSH)] = (short)pathv[k];
        __syncthreads();                           // publish nsc/SRr/records/path

        // ---- dual updates (scipy-exact op order) + augment ----
        const double minvF = minv;
        if (tid < Mm) {
            if (tid == cur_row)   uu[tid] += minvF;
            else if (SRr[tid])    uu[tid] += minvF - srow_val[tid];
            SRr[tid] = 0;
        }
        int S = nsc_lds;
        if (tid < S) {
            int jc = scol[tid];
            vvl[jc] -= (minvF - sval[tid]);
        }
        if (tid == 0) {
            int j = sink;
            for (;;) {
                int i2 = path_lds[j];
                row4col[j] = (short)i2;
                int nxt = col4row[i2];
                col4row[i2] = (short)j;
                j = nxt;
                if (i2 == cur_row) break;
            }
        }
        __syncthreads();
    }
    #undef RELAX

    // ---- emit (batch, src sorted ascending, tgt) ----
    if (tid < Mm) {
        int myj = col4row[tid];
        int rank = 0;
        #pragma unroll 4
        for (int t = 0; t < Mm; ++t) rank += (col4row[t] < myj) ? 1 : 0;
        out[b * Mm + tid] = b;                  // batch_idx
        out[Bb * Mm + b * Mm + rank] = myj;     // src_idx (sorted)
        out[2 * Bb * Mm + b * Mm + rank] = tid; // tgt_idx
    }
}

extern "C" void kernel_launch(void* const* d_in, const int* in_sizes, int n_in,
                              void* d_out, int out_size, void* d_ws, size_t ws_size,
                              hipStream_t stream) {
    (void)in_sizes; (void)n_in; (void)d_ws; (void)ws_size; (void)out_size;
    const float* predict_scores = (const float*)d_in[0];
    const float* predict_points = (const float*)d_in[1];
    const int*   scores         = (const int*)d_in[2];
    const float* points         = (const float*)d_in[3];
    int* out = (int*)d_out;
    hipLaunchKernelGGL(hungarian_kernel, dim3(Bb), dim3(Tt), 0, stream,
                       predict_scores, predict_points, scores, points, out);
}

// Round 6
// 510.770 us; speedup vs baseline: 1.1646x; 1.1646x over previous
//
#include <hip/hip_runtime.h>

// Batched Hungarian matcher — exact LSA, scipy-TRAJECTORY-exact.
//
// R11: R10 (542us, absmax 0) with the latency-bound reduce tails moved off
// the LDS pipe. Lexicographic (value, meta) min is associative+commutative,
// so reduction topology is free to change without touching the trajectory:
//   - wave reduce: 6-step DPP (row_ror:1/2/4/8 + row_bcast15/31) on the
//     VALU pipe (~14cy/step) replaces 6 __shfl_xor steps (ds_swizzle,
//     ~40-60cy each). Lane 63 ends with the wave min and writes the
//     candidate directly.
//   - cross-wave: each lane reads candidate (lane&7); 3-step DPP
//     row_ror:1/2/4 (rotation over the 8-periodic pattern covers all 8)
//     replaces 3 shfl_xor steps. readfirstlane -> uniform SGPRs.
//   - next-row data fetch: v_readlane with uniform lane index (SGPR)
//     replaces 3 ds_bpermute shfls; minv/ui/it0/it1 become SGPR operands.
//   - NaN-poison applied via uniform switch on ku=bj>>9 (scalar branch +
//     ~4 VALU) — R10's 8-way cmp/cndmask loop (~24 insts/pop) was the
//     regression; the in-relax NaN semantics stay (zero per-k cost).
// Evaluation order ((minv + cf) - u) - v, strictly-better updates, pop
// sequence and lowest-j tie-breaks bit-identical to scipy's _lsa.

#define Bb 32
#define Nn 4096
#define Mm 128
#define Tt 512
#define Kk (Nn / Tt)   // 8 columns per thread
#define TSH 9          // log2(Tt)
#define NW (Tt / 64)   // 8 waves
#define RECMAX 160

// One lexicographic-min combine step via DPP. Masked-off rows (row_mask)
// and invalid-source lanes receive old = {+INF, meta_max} and thus keep
// their current value. CTRL/RMASK must be literals.
#define DPP_CMB(CTRL, RMASK)                                                   \
    {                                                                          \
        int tlo = __builtin_amdgcn_update_dpp(0,          rlo, CTRL, RMASK, 0xF, false); \
        int thi = __builtin_amdgcn_update_dpp(0x7FF00000, rhi, CTRL, RMASK, 0xF, false); \
        int tmm = __builtin_amdgcn_update_dpp(0x7FFFFFFF, rmm, CTRL, RMASK, 0xF, false); \
        double tv = __hiloint2double(thi, tlo);                                \
        double cv = __hiloint2double(rhi, rlo);                                \
        bool tk = (tv < cv) || (tv == cv && tmm < rmm);                        \
        rlo = tk ? tlo : rlo; rhi = tk ? thi : rhi; rmm = tk ? tmm : rmm;      \
    }

__global__ __launch_bounds__(Tt, 1)
void hungarian_kernel(const float* __restrict__ predict_scores,
                      const float* __restrict__ predict_points,
                      const int*   __restrict__ scores,
                      const float* __restrict__ points,
                      int* __restrict__ out)
{
    __shared__ double vvl[Nn];           // column duals v (exact f64)
    __shared__ short  path_lds[Nn];      // predecessor row per column
    __shared__ short  row4col[Nn];       // matched row per column (-1 free)
    __shared__ double uu[Mm];            // row duals u
    __shared__ short  col4row[Mm];       // matched column per row (-1 free)
    __shared__ double srow_val[Mm];      // shortest[col4row[i]] at scan time
    __shared__ unsigned char SRr[Mm];    // scanned-row flags
    __shared__ float  tx0[Mm], tx1[Mm];
    __shared__ int    tch[Mm];
    __shared__ short  scol[RECMAX];      // popped (SC) columns this search
    __shared__ double sval[RECMAX];      // their pop values
    __shared__ int    nsc_lds;
    __shared__ double wv_[2][NW];        // per-wave candidate: value
    __shared__ int    wm_[2][NW];        //   meta (j<<8 | (r4+1))

    const int b    = blockIdx.x;
    const int tid  = threadIdx.x;
    const int lane = tid & 63;
    const int wid  = tid >> 6;
    const double INFD = __builtin_inf();
    const double NAND = __builtin_nan("");

    // ---- per-column data -> registers ----
    float negp0[Kk], negp1[Kk], qx0[Kk], qx1[Kk];
    const float* ps = predict_scores + (size_t)b * Nn * 2;
    const float* pp = predict_points + (size_t)b * Nn * 2;
    #pragma unroll
    for (int k = 0; k < Kk; ++k) {
        int j = tid + (k << TSH);
        float2 sc = ((const float2*)ps)[j];
        float mx = fmaxf(sc.x, sc.y);
        float e0 = expf(sc.x - mx), e1 = expf(sc.y - mx);
        float sm = e0 + e1;
        float n0 = -(e0 / sm), n1 = -(e1 / sm);
        float2 qp = ((const float2*)pp)[j];
        negp0[k] = n0; negp1[k] = n1;
        qx0[k] = qp.x; qx1[k] = qp.y;
        vvl[j] = 0.0;
        row4col[j] = -1;
    }
    if (tid < Mm) {
        col4row[tid] = -1;
        SRr[tid] = 0;
        uu[tid] = 0.0;                    // scipy: duals start at zero
        tx0[tid] = points[(size_t)b * Mm * 2 + 2 * tid];
        tx1[tid] = points[(size_t)b * Mm * 2 + 2 * tid + 1];
        tch[tid] = scores[(size_t)b * Mm + tid];
    }
    __syncthreads();

    // ---- wave-distributed row-data cache: lane l holds rows l, l+64 ----
    const float t0_c0 = tx0[lane], t0_c1 = tx0[lane + 64];
    const float t1_c0 = tx1[lane], t1_c1 = tx1[lane + 64];
    const int   ch_c0 = tch[lane], ch_c1 = tch[lane + 64];

    int pathv[Kk];                        // register path (published per search)
    #pragma unroll
    for (int k = 0; k < Kk; ++k) pathv[k] = 0;

    // relax body: PRES = per-class presence array (uniform per pop).
    // NaN-poisoned shr[k] (scanned cols): r < NaN and NaN < bv both false.
    #define RELAX(PRES)                                                        \
        _Pragma("unroll")                                                      \
        for (int k = 0; k < Kk; ++k) {                                         \
            float cf = PRES[k] + (fabsf(qx0[k] - it0) + fabsf(qx1[k] - it1));  \
            double r = ((minv + (double)cf) - ui) - vreg[k];                   \
            bool upd = r < shr[k];                                             \
            shr[k] = upd ? r : shr[k];                                         \
            pathv[k] = upd ? i : pathv[k];                                     \
            double sj = shr[k];                                                \
            if (sj < bv) { bv = sj; bm = premeta[k]; }                         \
        }

    // ---- JV: one shortest-augmenting-path search per row, scipy order ----
    for (int cur_row = 0; cur_row < Mm; ++cur_row) {
        // per-search register preload (constant within the search)
        double shr[Kk], vreg[Kk];
        int    premeta[Kk];
        double u_c0 = uu[lane], u_c1 = uu[lane + 64];   // u changes between searches
        #pragma unroll
        for (int k = 0; k < Kk; ++k) {
            int j = tid + (k << TSH);
            shr[k]  = INFD;
            vreg[k] = vvl[j];
            premeta[k] = (j << 8) | ((int)row4col[j] + 1);  // linear, conflict-free
        }
        int    i = cur_row;
        double minv = 0.0;
        int    sink = -1, par = 0, nsc = 0;
        double ui  = uu[cur_row];
        float  it0 = tx0[cur_row], it1 = tx1[cur_row];
        int    ich = __builtin_amdgcn_readfirstlane((tch[cur_row] == 1) ? 1 : 0);

        for (;;) {
            // ---- relax row i over all 4096 columns (exact f64, scipy order) ----
            double bv = INFD; int bm = 0x7FFFFFFF;
            if (ich) { RELAX(negp1) } else { RELAX(negp0) }

            // ---- wave reduce via DPP (VALU pipe): ror 1/2/4/8 gives every
            //      lane its 16-row min; bcast15 (rows 1,3) then bcast31
            //      (rows 2,3) fold rows -> lane 63 holds the wave min ----
            int rlo = __double2loint(bv), rhi = __double2hiint(bv), rmm = bm;
            DPP_CMB(0x121, 0xF)   // row_ror:1
            DPP_CMB(0x122, 0xF)   // row_ror:2
            DPP_CMB(0x124, 0xF)   // row_ror:4
            DPP_CMB(0x128, 0xF)   // row_ror:8
            DPP_CMB(0x142, 0xA)   // row_bcast15 -> rows 1,3
            DPP_CMB(0x143, 0xC)   // row_bcast31 -> rows 2,3
            if (lane == 63) {
                wv_[par][wid] = __hiloint2double(rhi, rlo);
                wm_[par][wid] = rmm;
            }
            __syncthreads();

            // ---- cross-wave: lane reads candidate (lane&7); 3-step DPP ror
            //      over the 8-periodic pattern -> all lanes hold global min ----
            {
                int l8 = lane & 7;
                double cv8 = wv_[par][l8];
                rlo = __double2loint(cv8); rhi = __double2hiint(cv8);
                rmm = wm_[par][l8];
            }
            DPP_CMB(0x121, 0xF)   // ror:1
            DPP_CMB(0x122, 0xF)   // ror:2
            DPP_CMB(0x124, 0xF)   // ror:4
            par ^= 1;
            int mm_s = __builtin_amdgcn_readfirstlane(rmm);
            minv = __hiloint2double(__builtin_amdgcn_readfirstlane(rhi),
                                    __builtin_amdgcn_readfirstlane(rlo));
            int bj = mm_s >> 8;               // uniform (SGPR)
            int r4 = (mm_s & 0xFF) - 1;       // uniform (SGPR)
            if (r4 < 0) {
                if (tid == 0) nsc_lds = nsc;
                sink = bj;
                break;                             // uniform exit
            }
            // ---- NaN-poison popped column: uniform switch on ku (scalar
            //      branch), one v_cmp + masked f64 mov in the taken case ----
            {
                const bool me = (tid == (bj & (Tt - 1)));
                switch (bj >> TSH) {
                    case 0: if (me) shr[0] = NAND; break;
                    case 1: if (me) shr[1] = NAND; break;
                    case 2: if (me) shr[2] = NAND; break;
                    case 3: if (me) shr[3] = NAND; break;
                    case 4: if (me) shr[4] = NAND; break;
                    case 5: if (me) shr[5] = NAND; break;
                    case 6: if (me) shr[6] = NAND; break;
                    default: if (me) shr[7] = NAND; break;
                }
            }
            if (tid == 0) {
                SRr[r4] = 1; srow_val[r4] = minv;
                scol[nsc] = (short)bj; sval[nsc] = minv; ++nsc;
            }
            // ---- next scan row's data via readlane (uniform lane idx) ----
            i = r4;
            {
                int  lx = r4 & 63;
                bool hi = r4 >= 64;                 // uniform
                double us = hi ? u_c1 : u_c0;
                float  f0 = hi ? t0_c1 : t0_c0;
                float  f1 = hi ? t1_c1 : t1_c0;
                int    cs = hi ? ch_c1 : ch_c0;
                ui  = __hiloint2double(
                        __builtin_amdgcn_readlane(__double2hiint(us), lx),
                        __builtin_amdgcn_readlane(__double2loint(us), lx));
                it0 = __int_as_float(
                        __builtin_amdgcn_readlane(__float_as_int(f0), lx));
                it1 = __int_as_float(
                        __builtin_amdgcn_readlane(__float_as_int(f1), lx));
                ich = (__builtin_amdgcn_readlane(cs, lx) == 1) ? 1 : 0;
            }
        }

        // ---- publish register paths (popped columns' values are final;
        //      never-popped columns' entries are never read) ----
        #pragma unroll
        for (int k = 0; k < Kk; ++k)
            path_lds[tid + (k << TSH)] = (short)pathv[k];
        __syncthreads();                           // publish nsc/SRr/records/path

        // ---- dual updates (scipy-exact op order) + augment ----
        const double minvF = minv;
        if (tid < Mm) {
            if (tid == cur_row)   uu[tid] += minvF;
            else if (SRr[tid])    uu[tid] += minvF - srow_val[tid];
            SRr[tid] = 0;
        }
        int S = nsc_lds;
        if (tid < S) {
            int jc = scol[tid];
            vvl[jc] -= (minvF - sval[tid]);
        }
        if (tid == 0) {
            int j = sink;
            for (;;) {
                int i2 = path_lds[j];
                row4col[j] = (short)i2;
                int nxt = col4row[i2];
                col4row[i2] = (short)j;
                j = nxt;
                if (i2 == cur_row) break;
            }
        }
        __syncthreads();
    }
    #undef RELAX

    // ---- emit (batch, src sorted ascending, tgt) ----
    if (tid < Mm) {
        int myj = col4row[tid];
        int rank = 0;
        #pragma unroll 4
        for (int t = 0; t < Mm; ++t) rank += (col4row[t] < myj) ? 1 : 0;
        out[b * Mm + tid] = b;                  // batch_idx
        out[Bb * Mm + b * Mm + rank] = myj;     // src_idx (sorted)
        out[2 * Bb * Mm + b * Mm + rank] = tid; // tgt_idx
    }
}

extern "C" void kernel_launch(void* const* d_in, const int* in_sizes, int n_in,
                              void* d_out, int out_size, void* d_ws, size_t ws_size,
                              hipStream_t stream) {
    (void)in_sizes; (void)n_in; (void)d_ws; (void)ws_size; (void)out_size;
    const float* predict_scores = (const float*)d_in[0];
    const float* predict_points = (const float*)d_in[1];
    const int*   scores         = (const int*)d_in[2];
    const float* points         = (const float*)d_in[3];
    int* out = (int*)d_out;
    hipLaunchKernelGGL(hungarian_kernel, dim3(Bb), dim3(Tt), 0, stream,
                       predict_scores, predict_points, scores, points, out);
}

// Round 7
// 484.844 us; speedup vs baseline: 1.2268x; 1.0535x over previous
//
#include <hip/hip_runtime.h>

// Batched Hungarian matcher — exact LSA, scipy-TRAJECTORY-exact.
//
// R12: R11 (458us, absmax 0) with all three reductions split into
// value-phase + meta-resolve. Lexicographic (value, meta) min == "min the
// values, then min the metas among value-achievers" at every stage
// (metas are distinct), so the pop sequence stays bit-identical to scipy:
//   - per-k: fmin tree (v_min_f64, minNum discards poison-NaNs) + sanitize
//     fmin(.,INF) for the all-NaN-lane edge + cmp_eq/meta-min tree.
//     Replaces the serial 8-step cmp/3-cndmask scan.
//   - wave: 4x ror-fmin (value) + resolve + 4x ror-imin (meta) + 2 cross-row
//     lexicographic folds (bcast15/31) -> lane 63. ~44 insts vs ~66.
//   - cross-wave: candidate packed {lo,hi,meta,0} -> ONE ds_write_b128 /
//     ds_read_b128; 3x ror-fmin + resolve + 3x ror-imin over the 8-periodic
//     pattern -> all lanes hold the global (minv, meta). ~17 insts vs ~33.
//   - epilogue: publish path_pack[j] = path | (pre-augment col4row[path])<<16
//     (gather once per search, parallel); tid0's serial augment walk then
//     needs ONE dependent LDS read per hop instead of two. Pre-augment
//     col4row is correct: along the alternating path all reads precede
//     writes and rows are distinct.
// Kept: meta=(j<<8)|(r4+1) (integer order == j order => scipy lowest-j
// tie-break), NaN-poison via uniform switch, readlane row fetch, scipy
// evaluation order ((minv + cf) - u) - v with strictly-better updates.

#define Bb 32
#define Nn 4096
#define Mm 128
#define Tt 512
#define Kk (Nn / Tt)   // 8 columns per thread
#define TSH 9          // log2(Tt)
#define NW (Tt / 64)   // 8 waves
#define RECMAX 160
#define IMAX 0x7FFFFFFF

// value-only DPP fmin step (minNum: NaN never propagates; invalid lanes get +INF)
#define DPP_VFMIN(CTRL)                                                        \
    {                                                                          \
        int tlo = __builtin_amdgcn_update_dpp(0,          vlo, CTRL, 0xF, 0xF, false); \
        int thi = __builtin_amdgcn_update_dpp(0x7FF00000, vhi, CTRL, 0xF, 0xF, false); \
        double tv = __hiloint2double(thi, tlo);                                \
        double cv0 = __hiloint2double(vhi, vlo);                               \
        double nv = fmin(cv0, tv);                                             \
        vlo = __double2loint(nv); vhi = __double2hiint(nv);                    \
    }
// meta-only DPP int-min step (invalid lanes get IMAX)
#define DPP_IMIN(CTRL)                                                         \
    {                                                                          \
        int tm = __builtin_amdgcn_update_dpp(IMAX, vmm, CTRL, 0xF, 0xF, false); \
        vmm = min(vmm, tm);                                                    \
    }
// lexicographic (value, meta) DPP fold (row-masked); invalid -> {+INF, IMAX}
#define DPP_LEX(CTRL, RMASK)                                                   \
    {                                                                          \
        int tlo = __builtin_amdgcn_update_dpp(0,          vlo, CTRL, RMASK, 0xF, false); \
        int thi = __builtin_amdgcn_update_dpp(0x7FF00000, vhi, CTRL, RMASK, 0xF, false); \
        int tmm = __builtin_amdgcn_update_dpp(IMAX,       vmm, CTRL, RMASK, 0xF, false); \
        double tv = __hiloint2double(thi, tlo);                                \
        double cv0 = __hiloint2double(vhi, vlo);                               \
        bool tk = (tv < cv0) || (tv == cv0 && tmm < vmm);                      \
        vlo = tk ? tlo : vlo; vhi = tk ? thi : vhi; vmm = tk ? tmm : vmm;      \
    }

__global__ __launch_bounds__(Tt, 1)
void hungarian_kernel(const float* __restrict__ predict_scores,
                      const float* __restrict__ predict_points,
                      const int*   __restrict__ scores,
                      const float* __restrict__ points,
                      int* __restrict__ out)
{
    __shared__ double vvl[Nn];           // column duals v (exact f64)
    __shared__ int    path_pack[Nn];     // (pre-augment col4row[path]<<16)|path
    __shared__ short  row4col[Nn];       // matched row per column (-1 free)
    __shared__ double uu[Mm];            // row duals u
    __shared__ short  col4row[Mm];       // matched column per row (-1 free)
    __shared__ double srow_val[Mm];      // shortest[col4row[i]] at scan time
    __shared__ unsigned char SRr[Mm];    // scanned-row flags
    __shared__ float  tx0[Mm], tx1[Mm];
    __shared__ int    tch[Mm];
    __shared__ short  scol[RECMAX];      // popped (SC) columns this search
    __shared__ double sval[RECMAX];      // their pop values
    __shared__ int    nsc_lds;
    __shared__ int4   wcand[2][NW];      // per-wave candidate {lo, hi, meta, 0}

    const int b    = blockIdx.x;
    const int tid  = threadIdx.x;
    const int lane = tid & 63;
    const int wid  = tid >> 6;
    const double INFD = __builtin_inf();
    const double NAND = __builtin_nan("");

    // ---- per-column data -> registers ----
    float negp0[Kk], negp1[Kk], qx0[Kk], qx1[Kk];
    const float* ps = predict_scores + (size_t)b * Nn * 2;
    const float* pp = predict_points + (size_t)b * Nn * 2;
    #pragma unroll
    for (int k = 0; k < Kk; ++k) {
        int j = tid + (k << TSH);
        float2 sc = ((const float2*)ps)[j];
        float mx = fmaxf(sc.x, sc.y);
        float e0 = expf(sc.x - mx), e1 = expf(sc.y - mx);
        float sm = e0 + e1;
        float n0 = -(e0 / sm), n1 = -(e1 / sm);
        float2 qp = ((const float2*)pp)[j];
        negp0[k] = n0; negp1[k] = n1;
        qx0[k] = qp.x; qx1[k] = qp.y;
        vvl[j] = 0.0;
        row4col[j] = -1;
    }
    if (tid < Mm) {
        col4row[tid] = -1;
        SRr[tid] = 0;
        uu[tid] = 0.0;                    // scipy: duals start at zero
        tx0[tid] = points[(size_t)b * Mm * 2 + 2 * tid];
        tx1[tid] = points[(size_t)b * Mm * 2 + 2 * tid + 1];
        tch[tid] = scores[(size_t)b * Mm + tid];
    }
    __syncthreads();

    // ---- wave-distributed row-data cache: lane l holds rows l, l+64 ----
    const float t0_c0 = tx0[lane], t0_c1 = tx0[lane + 64];
    const float t1_c0 = tx1[lane], t1_c1 = tx1[lane + 64];
    const int   ch_c0 = tch[lane], ch_c1 = tch[lane + 64];

    int pathv[Kk];                        // register path (published per search)
    #pragma unroll
    for (int k = 0; k < Kk; ++k) pathv[k] = 0;

    // relax body: update-only (selection moved to the fmin/meta trees).
    // NaN-poisoned shr[k] (scanned cols): r < NaN is false -> no update.
    #define RELAX(PRES)                                                        \
        _Pragma("unroll")                                                      \
        for (int k = 0; k < Kk; ++k) {                                         \
            float cf = PRES[k] + (fabsf(qx0[k] - it0) + fabsf(qx1[k] - it1));  \
            double r = ((minv + (double)cf) - ui) - vreg[k];                   \
            bool upd = r < shr[k];                                             \
            shr[k] = upd ? r : shr[k];                                         \
            pathv[k] = upd ? i : pathv[k];                                     \
        }

    // ---- JV: one shortest-augmenting-path search per row, scipy order ----
    for (int cur_row = 0; cur_row < Mm; ++cur_row) {
        // per-search register preload (constant within the search)
        double shr[Kk], vreg[Kk];
        int    premeta[Kk];
        double u_c0 = uu[lane], u_c1 = uu[lane + 64];   // u changes between searches
        #pragma unroll
        for (int k = 0; k < Kk; ++k) {
            int j = tid + (k << TSH);
            shr[k]  = INFD;
            vreg[k] = vvl[j];
            premeta[k] = (j << 8) | ((int)row4col[j] + 1);  // linear, conflict-free
        }
        int    i = cur_row;
        double minv = 0.0;
        int    sink = -1, par = 0, nsc = 0;
        double ui  = uu[cur_row];
        float  it0 = tx0[cur_row], it1 = tx1[cur_row];
        int    ich = __builtin_amdgcn_readfirstlane((tch[cur_row] == 1) ? 1 : 0);

        for (;;) {
            // ---- relax row i over all 4096 columns (exact f64, scipy order) ----
            if (ich) { RELAX(negp1) } else { RELAX(negp0) }

            // ---- per-lane selection: fmin tree + meta resolve ----
            double a0 = fmin(shr[0], shr[1]), a1 = fmin(shr[2], shr[3]);
            double a2 = fmin(shr[4], shr[5]), a3 = fmin(shr[6], shr[7]);
            double bv = fmin(fmin(fmin(a0, a1), fmin(a2, a3)), INFD); // all-NaN -> INF
            int c0 = (shr[0] == bv) ? premeta[0] : IMAX;
            int c1 = (shr[1] == bv) ? premeta[1] : IMAX;
            int c2 = (shr[2] == bv) ? premeta[2] : IMAX;
            int c3 = (shr[3] == bv) ? premeta[3] : IMAX;
            int c4 = (shr[4] == bv) ? premeta[4] : IMAX;
            int c5 = (shr[5] == bv) ? premeta[5] : IMAX;
            int c6 = (shr[6] == bv) ? premeta[6] : IMAX;
            int c7 = (shr[7] == bv) ? premeta[7] : IMAX;
            int bm = min(min(min(c0, c1), min(c2, c3)),
                         min(min(c4, c5), min(c6, c7)));

            // ---- wave reduce: value rors -> row min; resolve; meta rors;
            //      2 cross-row lexicographic folds -> lane 63 ----
            int vlo = __double2loint(bv), vhi = __double2hiint(bv), vmm;
            DPP_VFMIN(0x121) DPP_VFMIN(0x122) DPP_VFMIN(0x124) DPP_VFMIN(0x128)
            {
                double rv = __hiloint2double(vhi, vlo);   // 16-lane row min
                vmm = (bv == rv) ? bm : IMAX;
            }
            DPP_IMIN(0x121) DPP_IMIN(0x122) DPP_IMIN(0x124) DPP_IMIN(0x128)
            DPP_LEX(0x142, 0xA)   // row_bcast15 -> rows 1,3
            DPP_LEX(0x143, 0xC)   // row_bcast31 -> rows 2,3
            if (lane == 63) wcand[par][wid] = make_int4(vlo, vhi, vmm, 0);
            __syncthreads();

            // ---- cross-wave: one b128 read; value rors over the 8-periodic
            //      pattern; resolve; meta rors -> all lanes hold global min ----
            int4 cnd = wcand[par][lane & 7];
            double cv2 = __hiloint2double(cnd.y, cnd.x);
            int    cm2 = cnd.z;
            vlo = cnd.x; vhi = cnd.y;
            DPP_VFMIN(0x121) DPP_VFMIN(0x122) DPP_VFMIN(0x124)
            double gv = __hiloint2double(vhi, vlo);
            vmm = (cv2 == gv) ? cm2 : IMAX;
            DPP_IMIN(0x121) DPP_IMIN(0x122) DPP_IMIN(0x124)
            par ^= 1;
            minv = __hiloint2double(__builtin_amdgcn_readfirstlane(vhi),
                                    __builtin_amdgcn_readfirstlane(vlo));
            int mm_s = __builtin_amdgcn_readfirstlane(vmm);
            int bj = mm_s >> 8;               // uniform (SGPR)
            int r4 = (mm_s & 0xFF) - 1;       // uniform (SGPR)
            if (r4 < 0) {
                if (tid == 0) nsc_lds = nsc;
                sink = bj;
                break;                             // uniform exit
            }
            // ---- NaN-poison popped column: uniform switch, one lane hit ----
            {
                const bool me = (tid == (bj & (Tt - 1)));
                switch (bj >> TSH) {
                    case 0: if (me) shr[0] = NAND; break;
                    case 1: if (me) shr[1] = NAND; break;
                    case 2: if (me) shr[2] = NAND; break;
                    case 3: if (me) shr[3] = NAND; break;
                    case 4: if (me) shr[4] = NAND; break;
                    case 5: if (me) shr[5] = NAND; break;
                    case 6: if (me) shr[6] = NAND; break;
                    default: if (me) shr[7] = NAND; break;
                }
            }
            if (tid == 0) {
                SRr[r4] = 1; srow_val[r4] = minv;
                scol[nsc] = (short)bj; sval[nsc] = minv; ++nsc;
            }
            // ---- next scan row's data via readlane (uniform lane idx) ----
            i = r4;
            {
                int  lx = r4 & 63;
                bool hi = r4 >= 64;                 // uniform
                double us = hi ? u_c1 : u_c0;
                float  f0 = hi ? t0_c1 : t0_c0;
                float  f1 = hi ? t1_c1 : t1_c0;
                int    cs = hi ? ch_c1 : ch_c0;
                ui  = __hiloint2double(
                        __builtin_amdgcn_readlane(__double2hiint(us), lx),
                        __builtin_amdgcn_readlane(__double2loint(us), lx));
                it0 = __int_as_float(
                        __builtin_amdgcn_readlane(__float_as_int(f0), lx));
                it1 = __int_as_float(
                        __builtin_amdgcn_readlane(__float_as_int(f1), lx));
                ich = (__builtin_amdgcn_readlane(cs, lx) == 1) ? 1 : 0;
            }
        }

        // ---- publish packed paths: path | (pre-augment col4row[path] << 16).
        //      Popped columns' entries are final; never-popped never read. ----
        #pragma unroll
        for (int k = 0; k < Kk; ++k) {
            int pv = pathv[k];
            int cr = (int)(unsigned short)col4row[pv];
            path_pack[tid + (k << TSH)] = (pv & 0xFFFF) | (cr << 16);
        }
        __syncthreads();                           // publish nsc/SRr/records/path

        // ---- dual updates (scipy-exact op order) + augment ----
        const double minvF = minv;
        if (tid < Mm) {
            if (tid == cur_row)   uu[tid] += minvF;
            else if (SRr[tid])    uu[tid] += minvF - srow_val[tid];
            SRr[tid] = 0;
        }
        int S = nsc_lds;
        if (tid < S) {
            int jc = scol[tid];
            vvl[jc] -= (minvF - sval[tid]);
        }
        if (tid == 0) {
            int j = sink;
            for (;;) {
                int pk = path_pack[j];            // ONE read per hop
                int i2 = pk & 0xFFFF;
                row4col[j] = (short)i2;
                col4row[i2] = (short)j;
                if (i2 == cur_row) break;
                j = (pk >> 16) & 0xFFFF;          // pre-augment col4row[i2]
            }
        }
        __syncthreads();
    }
    #undef RELAX

    // ---- emit (batch, src sorted ascending, tgt) ----
    if (tid < Mm) {
        int myj = col4row[tid];
        int rank = 0;
        #pragma unroll 4
        for (int t = 0; t < Mm; ++t) rank += (col4row[t] < myj) ? 1 : 0;
        out[b * Mm + tid] = b;                  // batch_idx
        out[Bb * Mm + b * Mm + rank] = myj;     // src_idx (sorted)
        out[2 * Bb * Mm + b * Mm + rank] = tid; // tgt_idx
    }
}

extern "C" void kernel_launch(void* const* d_in, const int* in_sizes, int n_in,
                              void* d_out, int out_size, void* d_ws, size_t ws_size,
                              hipStream_t stream) {
    (void)in_sizes; (void)n_in; (void)d_ws; (void)ws_size; (void)out_size;
    const float* predict_scores = (const float*)d_in[0];
    const float* predict_points = (const float*)d_in[1];
    const int*   scores         = (const int*)d_in[2];
    const float* points         = (const float*)d_in[3];
    int* out = (int*)d_out;
    hipLaunchKernelGGL(hungarian_kernel, dim3(Bb), dim3(Tt), 0, stream,
                       predict_scores, predict_points, scores, points, out);
}